// Round 1
// baseline (4204.128 us; speedup 1.0000x reference)
//
#include <hip/hip_runtime.h>
#include <hip/hip_bf16.h>
#include <math.h>

#define HID 128
#define SLOPE 0.01f
#define LN_EPS 1e-5f

__global__ void fill_kernel(float* __restrict__ p, float v, int n) {
  int i = blockIdx.x * blockDim.x + threadIdx.x;
  if (i < n) p[i] = v;
}

__global__ void deg_kernel(const int* __restrict__ dst, float* __restrict__ deg, int E) {
  int i = blockIdx.x * blockDim.x + threadIdx.x;
  if (i < E) atomicAdd(&deg[dst[i]], 1.0f);
}

__global__ void rsqrt_kernel(float* __restrict__ d, int n) {
  int i = blockIdx.x * blockDim.x + threadIdx.x;
  if (i < n) d[i] = rsqrtf(d[i]);
}

// out[n][j] = bias[j] + sum_k feat[n][k] * W[k][j]   (block = 1 row, 128 threads)
template<int DIM>
__global__ void dense_kernel(const float* __restrict__ feat,
                             const float* __restrict__ W,
                             const float* __restrict__ bias,
                             float* __restrict__ out, int nrows) {
  __shared__ float sf[DIM];
  int n = blockIdx.x;
  int j = threadIdx.x;
  if (j < DIM) sf[j] = feat[(size_t)n * DIM + j];
  __syncthreads();
  float acc = bias ? bias[j] : 0.0f;
#pragma unroll
  for (int k = 0; k < DIM; ++k) acc = fmaf(sf[k], W[k * HID + j], acc);
  out[(size_t)n * HID + j] = acc;
}

// agg[n][:] = xw[n][:] * dinv[n]^2   (self-loop term; also initializes agg)
__global__ void selfloop_kernel(const float* __restrict__ xw, const float* __restrict__ dinv,
                                float* __restrict__ agg, int n_nodes) {
  int t = blockIdx.x * blockDim.x + threadIdx.x;
  int total = n_nodes * (HID / 4);
  if (t >= total) return;
  int n = t >> 5;  // HID/4 = 32 float4 per row
  float w = dinv[n]; w *= w;
  float4 v = reinterpret_cast<const float4*>(xw)[t];
  v.x *= w; v.y *= w; v.z *= w; v.w *= w;
  reinterpret_cast<float4*>(agg)[t] = v;
}

// one wave per edge: agg[dst] += xw[src] * dinv[src]*dinv[dst]
__global__ void scatter_kernel(const int* __restrict__ src, const int* __restrict__ dst,
                               const float* __restrict__ dinv,
                               const float* __restrict__ xw,
                               float* __restrict__ agg, int E) {
  int wid = (blockIdx.x * blockDim.x + threadIdx.x) >> 6;
  int lane = threadIdx.x & 63;
  if (wid >= E) return;
  int s = src[wid], d = dst[wid];
  float w = dinv[s] * dinv[d];
  float2 a = reinterpret_cast<const float2*>(xw + (size_t)s * HID)[lane];
  float* dp = agg + (size_t)d * HID + 2 * lane;
  atomicAdd(dp, a.x * w);
  atomicAdd(dp + 1, a.y * w);
}

// h = agg + cb; LayerNorm(h)*g + b; LeakyReLU -> out.  One wave per node.
__global__ void norm_act_kernel(const float* __restrict__ agg,
                                const float* __restrict__ cb,
                                const float* __restrict__ g,
                                const float* __restrict__ b,
                                float* __restrict__ out, int n_nodes) {
  int n = blockIdx.x * 4 + (threadIdx.x >> 6);
  if (n >= n_nodes) return;
  int lane = threadIdx.x & 63;
  float2 v = reinterpret_cast<const float2*>(agg + (size_t)n * HID)[lane];
  float2 cb2 = reinterpret_cast<const float2*>(cb)[lane];
  v.x += cb2.x; v.y += cb2.y;
  float s = v.x + v.y;
#pragma unroll
  for (int m = 1; m < 64; m <<= 1) s += __shfl_xor(s, m);
  float mu = s * (1.0f / HID);
  float dx = v.x - mu, dy = v.y - mu;
  float sq = dx * dx + dy * dy;
#pragma unroll
  for (int m = 1; m < 64; m <<= 1) sq += __shfl_xor(sq, m);
  float rs = rsqrtf(sq * (1.0f / HID) + LN_EPS);
  float2 g2 = reinterpret_cast<const float2*>(g)[lane];
  float2 b2 = reinterpret_cast<const float2*>(b)[lane];
  float o0 = dx * rs * g2.x + b2.x;
  float o1 = dy * rs * g2.y + b2.y;
  o0 = o0 >= 0.0f ? o0 : SLOPE * o0;
  o1 = o1 >= 0.0f ? o1 : SLOPE * o1;
  reinterpret_cast<float2*>(out + (size_t)n * HID)[lane] = make_float2(o0, o1);
}

// one wave per prediction pair
__global__ void pred_kernel(const int* __restrict__ eu, const int* __restrict__ ef,
                            const float* __restrict__ x,
                            const float* __restrict__ eW, const float* __restrict__ eb,
                            const float* __restrict__ rW, const float* __restrict__ rb,
                            float* __restrict__ out_exist, float* __restrict__ out_rating,
                            int Ep) {
  int wid = (blockIdx.x * blockDim.x + threadIdx.x) >> 6;
  int lane = threadIdx.x & 63;
  if (wid >= Ep) return;
  int u = eu[wid], f = ef[wid];
  float2 xu = reinterpret_cast<const float2*>(x + (size_t)u * HID)[lane];
  float2 xf = reinterpret_cast<const float2*>(x + (size_t)f * HID)[lane];
  float2 eWu = reinterpret_cast<const float2*>(eW)[lane];
  float2 eWf = reinterpret_cast<const float2*>(eW + HID)[lane];
  float2 rWu = reinterpret_cast<const float2*>(rW)[lane];
  float2 rWf = reinterpret_cast<const float2*>(rW + HID)[lane];
  float pe = xu.x * eWu.x + xu.y * eWu.y + xf.x * eWf.x + xf.y * eWf.y;
  float pr = xu.x * rWu.x + xu.y * rWu.y + xf.x * rWf.x + xf.y * rWf.y;
#pragma unroll
  for (int m = 1; m < 64; m <<= 1) {
    pe += __shfl_xor(pe, m);
    pr += __shfl_xor(pr, m);
  }
  if (lane == 0) {
    out_exist[wid]  = 1.0f / (1.0f + expf(-(pe + eb[0])));
    out_rating[wid] = 1.0f + 4.0f / (1.0f + expf(-(pr + rb[0])));
  }
}

extern "C" void kernel_launch(void* const* d_in, const int* in_sizes, int n_in,
                              void* d_out, int out_size, void* d_ws, size_t ws_size,
                              hipStream_t stream) {
  const float* u_feat = (const float*)d_in[0];
  const float* f_feat = (const float*)d_in[1];
  const int*   ei     = (const int*)d_in[2];
  const int*   eu     = (const int*)d_in[3];
  const int*   ef     = (const int*)d_in[4];
  const float* u_W  = (const float*)d_in[5];
  const float* u_b  = (const float*)d_in[6];
  const float* f_W  = (const float*)d_in[7];
  const float* f_b  = (const float*)d_in[8];
  const float* c1_W = (const float*)d_in[9];
  const float* c1_b = (const float*)d_in[10];
  const float* c2_W = (const float*)d_in[11];
  const float* c2_b = (const float*)d_in[12];
  const float* n1_g = (const float*)d_in[13];
  const float* n1_b = (const float*)d_in[14];
  const float* n2_g = (const float*)d_in[15];
  const float* n2_b = (const float*)d_in[16];
  const float* e_W  = (const float*)d_in[17];
  const float* e_b  = (const float*)d_in[18];
  const float* r_W  = (const float*)d_in[19];
  const float* r_b  = (const float*)d_in[20];

  int n_u = in_sizes[0] / 64;
  int n_f = in_sizes[1] / HID;
  int n   = n_u + n_f;
  int E   = in_sizes[2] / 2;
  int Ep  = in_sizes[3];

  float* x    = (float*)d_ws;
  float* xw   = x + (size_t)n * HID;
  float* agg  = xw + (size_t)n * HID;
  float* dinv = agg + (size_t)n * HID;

  const int* src = ei;
  const int* dst = ei + E;

  // degree (with self loop) -> dinv = rsqrt(deg)
  fill_kernel<<<(n + 255) / 256, 256, 0, stream>>>(dinv, 1.0f, n);
  deg_kernel<<<(E + 255) / 256, 256, 0, stream>>>(dst, dinv, E);
  rsqrt_kernel<<<(n + 255) / 256, 256, 0, stream>>>(dinv, n);

  // input embeddings
  dense_kernel<64><<<n_u, HID, 0, stream>>>(u_feat, u_W, u_b, x, n_u);
  dense_kernel<HID><<<n_f, HID, 0, stream>>>(f_feat, f_W, f_b, x + (size_t)n_u * HID, n_f);

  for (int layer = 0; layer < 2; ++layer) {
    const float* cW = layer ? c2_W : c1_W;
    const float* cb = layer ? c2_b : c1_b;
    const float* g  = layer ? n2_g : n1_g;
    const float* bb = layer ? n2_b : n1_b;
    dense_kernel<HID><<<n, HID, 0, stream>>>(x, cW, nullptr, xw, n);
    selfloop_kernel<<<((n * (HID / 4)) + 255) / 256, 256, 0, stream>>>(xw, dinv, agg, n);
    scatter_kernel<<<(E + 3) / 4, 256, 0, stream>>>(src, dst, dinv, xw, agg, E);
    norm_act_kernel<<<(n + 3) / 4, 256, 0, stream>>>(agg, cb, g, bb, x, n);
  }

  float* out_exist  = (float*)d_out;
  float* out_rating = out_exist + Ep;
  pred_kernel<<<(Ep + 3) / 4, 256, 0, stream>>>(eu, ef, x, e_W, e_b, r_W, r_b,
                                                out_exist, out_rating, Ep);
}

// Round 2
// 1421.925 us; speedup vs baseline: 2.9566x; 2.9566x over previous
//
#include <hip/hip_runtime.h>
#include <hip/hip_bf16.h>
#include <math.h>

#define HID 128
#define SLOPE 0.01f
#define LN_EPS 1e-5f
#define SCAN_T 1024

__global__ void zero_int_kernel(int* __restrict__ p, int n) {
  int i = blockIdx.x * blockDim.x + threadIdx.x;
  if (i < n) p[i] = 0;
}

__global__ void hist_kernel(const int* __restrict__ dst, int* __restrict__ cnt, int E) {
  int i = blockIdx.x * blockDim.x + threadIdx.x;
  if (i < E) atomicAdd(&cnt[dst[i]], 1);
}

// single-block scan: cnt[0..n) -> rowptr (exclusive), dinv = rsqrt(cnt+1)
__global__ void scan_kernel(const int* __restrict__ cnt, int* __restrict__ rowptr,
                            float* __restrict__ dinv, int n) {
  __shared__ int ssum[SCAN_T];
  int t = threadIdx.x;
  int chunk = (n + SCAN_T - 1) / SCAN_T;
  int beg = t * chunk, end = min(beg + chunk, n);
  int s = 0;
  for (int i = beg; i < end; ++i) s += cnt[i];
  ssum[t] = s;
  __syncthreads();
  for (int off = 1; off < SCAN_T; off <<= 1) {
    int v = (t >= off) ? ssum[t - off] : 0;
    __syncthreads();
    ssum[t] += v;
    __syncthreads();
  }
  int pre = (t == 0) ? 0 : ssum[t - 1];
  for (int i = beg; i < end; ++i) {
    rowptr[i] = pre;
    int c = cnt[i];
    dinv[i] = rsqrtf((float)(c + 1));
    pre += c;
  }
  if (t == SCAN_T - 1) rowptr[n] = pre;
}

__global__ void fill_csr_kernel(const int* __restrict__ src, const int* __restrict__ dst,
                                const int* __restrict__ rowptr, int* __restrict__ cursor,
                                const float* __restrict__ dinv,
                                int* __restrict__ colsrc, float* __restrict__ colw, int E) {
  int e = blockIdx.x * blockDim.x + threadIdx.x;
  if (e >= E) return;
  int s = src[e], d = dst[e];
  int pos = atomicAdd(&cursor[d], 1);
  int idx = rowptr[d] + pos;
  colsrc[idx] = s;
  colw[idx] = dinv[s] * dinv[d];
}

// out[n][j] = bias[j] + sum_k feat[n][k] * W[k][j]   (block = 1 row, 128 threads)
template<int DIM>
__global__ void dense_kernel(const float* __restrict__ feat,
                             const float* __restrict__ W,
                             const float* __restrict__ bias,
                             float* __restrict__ out, int nrows) {
  __shared__ float sf[DIM];
  int n = blockIdx.x;
  int j = threadIdx.x;
  if (j < DIM) sf[j] = feat[(size_t)n * DIM + j];
  __syncthreads();
  float acc = bias ? bias[j] : 0.0f;
#pragma unroll
  for (int k = 0; k < DIM; ++k) acc = fmaf(sf[k], W[k * HID + j], acc);
  out[(size_t)n * HID + j] = acc;
}

// One wave per dst node: acc = xw[d]*dinv[d]^2 + sum_edges xw[s]*w; then
// + conv bias, LayerNorm * g + b, LeakyReLU -> out.
__global__ void gather_norm_kernel(const int* __restrict__ rowptr,
                                   const int* __restrict__ colsrc,
                                   const float* __restrict__ colw,
                                   const float* __restrict__ xw,
                                   const float* __restrict__ dinv,
                                   const float* __restrict__ cb,
                                   const float* __restrict__ g,
                                   const float* __restrict__ b,
                                   float* __restrict__ out, int n_nodes) {
  int d = blockIdx.x * 4 + (threadIdx.x >> 6);
  if (d >= n_nodes) return;
  int lane = threadIdx.x & 63;
  float wd = dinv[d];
  float wself = wd * wd;
  float2 v = reinterpret_cast<const float2*>(xw + (size_t)d * HID)[lane];
  float ax = v.x * wself, ay = v.y * wself;
  int beg = rowptr[d], end = rowptr[d + 1];
  int j = beg;
  for (; j + 1 < end; j += 2) {
    int s0 = colsrc[j], s1 = colsrc[j + 1];
    float w0 = colw[j], w1 = colw[j + 1];
    float2 a0 = reinterpret_cast<const float2*>(xw + (size_t)s0 * HID)[lane];
    float2 a1 = reinterpret_cast<const float2*>(xw + (size_t)s1 * HID)[lane];
    ax += a0.x * w0 + a1.x * w1;
    ay += a0.y * w0 + a1.y * w1;
  }
  if (j < end) {
    int s0 = colsrc[j];
    float w0 = colw[j];
    float2 a0 = reinterpret_cast<const float2*>(xw + (size_t)s0 * HID)[lane];
    ax += a0.x * w0;
    ay += a0.y * w0;
  }
  float2 cb2 = reinterpret_cast<const float2*>(cb)[lane];
  ax += cb2.x; ay += cb2.y;
  float s = ax + ay;
#pragma unroll
  for (int m = 1; m < 64; m <<= 1) s += __shfl_xor(s, m);
  float mu = s * (1.0f / HID);
  float dx = ax - mu, dy = ay - mu;
  float sq = dx * dx + dy * dy;
#pragma unroll
  for (int m = 1; m < 64; m <<= 1) sq += __shfl_xor(sq, m);
  float rs = rsqrtf(sq * (1.0f / HID) + LN_EPS);
  float2 g2 = reinterpret_cast<const float2*>(g)[lane];
  float2 b2 = reinterpret_cast<const float2*>(b)[lane];
  float o0 = dx * rs * g2.x + b2.x;
  float o1 = dy * rs * g2.y + b2.y;
  o0 = o0 >= 0.0f ? o0 : SLOPE * o0;
  o1 = o1 >= 0.0f ? o1 : SLOPE * o1;
  reinterpret_cast<float2*>(out + (size_t)d * HID)[lane] = make_float2(o0, o1);
}

// one wave per prediction pair
__global__ void pred_kernel(const int* __restrict__ eu, const int* __restrict__ ef,
                            const float* __restrict__ x,
                            const float* __restrict__ eW, const float* __restrict__ eb,
                            const float* __restrict__ rW, const float* __restrict__ rb,
                            float* __restrict__ out_exist, float* __restrict__ out_rating,
                            int Ep) {
  int wid = (blockIdx.x * blockDim.x + threadIdx.x) >> 6;
  int lane = threadIdx.x & 63;
  if (wid >= Ep) return;
  int u = eu[wid], f = ef[wid];
  float2 xu = reinterpret_cast<const float2*>(x + (size_t)u * HID)[lane];
  float2 xf = reinterpret_cast<const float2*>(x + (size_t)f * HID)[lane];
  float2 eWu = reinterpret_cast<const float2*>(eW)[lane];
  float2 eWf = reinterpret_cast<const float2*>(eW + HID)[lane];
  float2 rWu = reinterpret_cast<const float2*>(rW)[lane];
  float2 rWf = reinterpret_cast<const float2*>(rW + HID)[lane];
  float pe = xu.x * eWu.x + xu.y * eWu.y + xf.x * eWf.x + xf.y * eWf.y;
  float pr = xu.x * rWu.x + xu.y * rWu.y + xf.x * rWf.x + xf.y * rWf.y;
#pragma unroll
  for (int m = 1; m < 64; m <<= 1) {
    pe += __shfl_xor(pe, m);
    pr += __shfl_xor(pr, m);
  }
  if (lane == 0) {
    out_exist[wid]  = 1.0f / (1.0f + expf(-(pe + eb[0])));
    out_rating[wid] = 1.0f + 4.0f / (1.0f + expf(-(pr + rb[0])));
  }
}

extern "C" void kernel_launch(void* const* d_in, const int* in_sizes, int n_in,
                              void* d_out, int out_size, void* d_ws, size_t ws_size,
                              hipStream_t stream) {
  const float* u_feat = (const float*)d_in[0];
  const float* f_feat = (const float*)d_in[1];
  const int*   ei     = (const int*)d_in[2];
  const int*   eu     = (const int*)d_in[3];
  const int*   ef     = (const int*)d_in[4];
  const float* u_W  = (const float*)d_in[5];
  const float* u_b  = (const float*)d_in[6];
  const float* f_W  = (const float*)d_in[7];
  const float* f_b  = (const float*)d_in[8];
  const float* c1_W = (const float*)d_in[9];
  const float* c1_b = (const float*)d_in[10];
  const float* c2_W = (const float*)d_in[11];
  const float* c2_b = (const float*)d_in[12];
  const float* n1_g = (const float*)d_in[13];
  const float* n1_b = (const float*)d_in[14];
  const float* n2_g = (const float*)d_in[15];
  const float* n2_b = (const float*)d_in[16];
  const float* e_W  = (const float*)d_in[17];
  const float* e_b  = (const float*)d_in[18];
  const float* r_W  = (const float*)d_in[19];
  const float* r_b  = (const float*)d_in[20];

  int n_u = in_sizes[0] / 64;
  int n_f = in_sizes[1] / HID;
  int n   = n_u + n_f;
  int E   = in_sizes[2] / 2;
  int Ep  = in_sizes[3];

  const int* src = ei;
  const int* dst = ei + E;

  float* x      = (float*)d_ws;                    // n*HID f32
  float* xw     = x + (size_t)n * HID;             // n*HID f32
  float* dinv   = xw + (size_t)n * HID;            // n f32
  float* colw   = dinv + n;                        // E f32
  int*   cnt    = (int*)(colw + E);                // n int
  int*   rowptr = cnt + n;                         // n+1 int
  int*   cursor = rowptr + n + 1;                  // n int
  int*   colsrc = cursor + n;                      // E int

  // ---- build CSR by dst + dinv ----
  zero_int_kernel<<<(n + 255) / 256, 256, 0, stream>>>(cnt, n);
  hist_kernel<<<(E + 255) / 256, 256, 0, stream>>>(dst, cnt, E);
  scan_kernel<<<1, SCAN_T, 0, stream>>>(cnt, rowptr, dinv, n);
  zero_int_kernel<<<(n + 255) / 256, 256, 0, stream>>>(cursor, n);
  fill_csr_kernel<<<(E + 255) / 256, 256, 0, stream>>>(src, dst, rowptr, cursor, dinv,
                                                       colsrc, colw, E);

  // ---- input embeddings ----
  dense_kernel<64><<<n_u, HID, 0, stream>>>(u_feat, u_W, u_b, x, n_u);
  dense_kernel<HID><<<n_f, HID, 0, stream>>>(f_feat, f_W, f_b, x + (size_t)n_u * HID, n_f);

  // ---- 2 GCN layers ----
  for (int layer = 0; layer < 2; ++layer) {
    const float* cW = layer ? c2_W : c1_W;
    const float* cb = layer ? c2_b : c1_b;
    const float* g  = layer ? n2_g : n1_g;
    const float* bb = layer ? n2_b : n1_b;
    dense_kernel<HID><<<n, HID, 0, stream>>>(x, cW, nullptr, xw, n);
    gather_norm_kernel<<<(n + 3) / 4, 256, 0, stream>>>(rowptr, colsrc, colw, xw, dinv,
                                                        cb, g, bb, x, n);
  }

  // ---- prediction heads ----
  float* out_exist  = (float*)d_out;
  float* out_rating = out_exist + Ep;
  pred_kernel<<<(Ep + 3) / 4, 256, 0, stream>>>(eu, ef, x, e_W, e_b, r_W, r_b,
                                                out_exist, out_rating, Ep);
}

// Round 3
// 1072.114 us; speedup vs baseline: 3.9213x; 1.3263x over previous
//
#include <hip/hip_runtime.h>
#include <hip/hip_bf16.h>
#include <math.h>

#define HID 128
#define SLOPE 0.01f
#define LN_EPS 1e-5f
#define SCAN_T 1024

__global__ void zero_int_kernel(int* __restrict__ p, int n) {
  int i = blockIdx.x * blockDim.x + threadIdx.x;
  if (i < n) p[i] = 0;
}

__global__ void hist_kernel(const int* __restrict__ dst, int* __restrict__ cnt, int E) {
  int i = blockIdx.x * blockDim.x + threadIdx.x;
  if (i < E) atomicAdd(&cnt[dst[i]], 1);
}

// single-block scan: cnt[0..n) -> rowptr (exclusive), dinv = rsqrt(cnt+1)
__global__ void scan_kernel(const int* __restrict__ cnt, int* __restrict__ rowptr,
                            float* __restrict__ dinv, int n) {
  __shared__ int ssum[SCAN_T];
  int t = threadIdx.x;
  int chunk = (n + SCAN_T - 1) / SCAN_T;
  int beg = t * chunk, end = min(beg + chunk, n);
  int s = 0;
  for (int i = beg; i < end; ++i) s += cnt[i];
  ssum[t] = s;
  __syncthreads();
  for (int off = 1; off < SCAN_T; off <<= 1) {
    int v = (t >= off) ? ssum[t - off] : 0;
    __syncthreads();
    ssum[t] += v;
    __syncthreads();
  }
  int pre = (t == 0) ? 0 : ssum[t - 1];
  for (int i = beg; i < end; ++i) {
    rowptr[i] = pre;
    int c = cnt[i];
    dinv[i] = rsqrtf((float)(c + 1));
    pre += c;
  }
  if (t == SCAN_T - 1) rowptr[n] = pre;
}

__global__ void fill_csr_kernel(const int* __restrict__ src, const int* __restrict__ dst,
                                const int* __restrict__ rowptr, int* __restrict__ cursor,
                                const float* __restrict__ dinv,
                                int* __restrict__ colsrc, float* __restrict__ colw, int E) {
  int e = blockIdx.x * blockDim.x + threadIdx.x;
  if (e >= E) return;
  int s = src[e], d = dst[e];
  int pos = atomicAdd(&cursor[d], 1);
  int idx = rowptr[d] + pos;
  colsrc[idx] = s;
  colw[idx] = dinv[s] * dinv[d];
}

// out[n][j] = bias[j] + sum_k feat[n][k] * W[k][j]   (block = 1 row, 128 threads)
template<int DIM>
__global__ void dense_kernel(const float* __restrict__ feat,
                             const float* __restrict__ W,
                             const float* __restrict__ bias,
                             float* __restrict__ out, int nrows) {
  __shared__ float sf[DIM];
  int n = blockIdx.x;
  int j = threadIdx.x;
  if (j < DIM) sf[j] = feat[(size_t)n * DIM + j];
  __syncthreads();
  float acc = bias ? bias[j] : 0.0f;
#pragma unroll
  for (int k = 0; k < DIM; ++k) acc = fmaf(sf[k], W[k * HID + j], acc);
  out[(size_t)n * HID + j] = acc;
}

// One wave per dst node: acc = xw[d]*dinv[d]^2 + sum_edges xw[s]*w; then
// + conv bias, LayerNorm * g + b, LeakyReLU -> out.
__global__ void gather_norm_kernel(const int* __restrict__ rowptr,
                                   const int* __restrict__ colsrc,
                                   const float* __restrict__ colw,
                                   const float* __restrict__ xw,
                                   const float* __restrict__ dinv,
                                   const float* __restrict__ cb,
                                   const float* __restrict__ g,
                                   const float* __restrict__ b,
                                   float* __restrict__ out, int n_nodes) {
  int d = blockIdx.x * 4 + (threadIdx.x >> 6);
  if (d >= n_nodes) return;
  int lane = threadIdx.x & 63;
  float wd = dinv[d];
  float wself = wd * wd;
  float2 v = reinterpret_cast<const float2*>(xw + (size_t)d * HID)[lane];
  float ax = v.x * wself, ay = v.y * wself;
  int beg = rowptr[d], end = rowptr[d + 1];
  int j = beg;
  for (; j + 1 < end; j += 2) {
    int s0 = colsrc[j], s1 = colsrc[j + 1];
    float w0 = colw[j], w1 = colw[j + 1];
    float2 a0 = reinterpret_cast<const float2*>(xw + (size_t)s0 * HID)[lane];
    float2 a1 = reinterpret_cast<const float2*>(xw + (size_t)s1 * HID)[lane];
    ax += a0.x * w0 + a1.x * w1;
    ay += a0.y * w0 + a1.y * w1;
  }
  if (j < end) {
    int s0 = colsrc[j];
    float w0 = colw[j];
    float2 a0 = reinterpret_cast<const float2*>(xw + (size_t)s0 * HID)[lane];
    ax += a0.x * w0;
    ay += a0.y * w0;
  }
  float2 cb2 = reinterpret_cast<const float2*>(cb)[lane];
  ax += cb2.x; ay += cb2.y;
  float s = ax + ay;
#pragma unroll
  for (int m = 1; m < 64; m <<= 1) s += __shfl_xor(s, m);
  float mu = s * (1.0f / HID);
  float dx = ax - mu, dy = ay - mu;
  float sq = dx * dx + dy * dy;
#pragma unroll
  for (int m = 1; m < 64; m <<= 1) sq += __shfl_xor(sq, m);
  float rs = rsqrtf(sq * (1.0f / HID) + LN_EPS);
  float2 g2 = reinterpret_cast<const float2*>(g)[lane];
  float2 b2 = reinterpret_cast<const float2*>(b)[lane];
  float o0 = dx * rs * g2.x + b2.x;
  float o1 = dy * rs * g2.y + b2.y;
  o0 = o0 >= 0.0f ? o0 : SLOPE * o0;
  o1 = o1 >= 0.0f ? o1 : SLOPE * o1;
  reinterpret_cast<float2*>(out + (size_t)d * HID)[lane] = make_float2(o0, o1);
}

// Per-node projection table: table[n] = {x·eW[:H], x·eW[H:], x·rW[:H], x·rW[H:]}
__global__ void node_proj_kernel(const float* __restrict__ x,
                                 const float* __restrict__ eW,
                                 const float* __restrict__ rW,
                                 float4* __restrict__ table, int n_nodes) {
  int nd = blockIdx.x * 4 + (threadIdx.x >> 6);
  if (nd >= n_nodes) return;
  int lane = threadIdx.x & 63;
  float2 xv  = reinterpret_cast<const float2*>(x + (size_t)nd * HID)[lane];
  float2 eWu = reinterpret_cast<const float2*>(eW)[lane];
  float2 eWf = reinterpret_cast<const float2*>(eW + HID)[lane];
  float2 rWu = reinterpret_cast<const float2*>(rW)[lane];
  float2 rWf = reinterpret_cast<const float2*>(rW + HID)[lane];
  float a = xv.x * eWu.x + xv.y * eWu.y;
  float b = xv.x * eWf.x + xv.y * eWf.y;
  float c = xv.x * rWu.x + xv.y * rWu.y;
  float d = xv.x * rWf.x + xv.y * rWf.y;
#pragma unroll
  for (int m = 1; m < 64; m <<= 1) {
    a += __shfl_xor(a, m);
    b += __shfl_xor(b, m);
    c += __shfl_xor(c, m);
    d += __shfl_xor(d, m);
  }
  if (lane == 0) table[nd] = make_float4(a, b, c, d);
}

// one thread per prediction pair
__global__ void pair_kernel(const int* __restrict__ eu, const int* __restrict__ ef,
                            const float4* __restrict__ table,
                            const float* __restrict__ eb, const float* __restrict__ rb,
                            float* __restrict__ out_exist, float* __restrict__ out_rating,
                            int Ep) {
  int i = blockIdx.x * blockDim.x + threadIdx.x;
  if (i >= Ep) return;
  float4 tu = table[eu[i]];
  float4 tf = table[ef[i]];
  float pe = tu.x + tf.y + eb[0];
  float pr = tu.z + tf.w + rb[0];
  out_exist[i]  = 1.0f / (1.0f + expf(-pe));
  out_rating[i] = 1.0f + 4.0f / (1.0f + expf(-pr));
}

extern "C" void kernel_launch(void* const* d_in, const int* in_sizes, int n_in,
                              void* d_out, int out_size, void* d_ws, size_t ws_size,
                              hipStream_t stream) {
  const float* u_feat = (const float*)d_in[0];
  const float* f_feat = (const float*)d_in[1];
  const int*   ei     = (const int*)d_in[2];
  const int*   eu     = (const int*)d_in[3];
  const int*   ef     = (const int*)d_in[4];
  const float* u_W  = (const float*)d_in[5];
  const float* u_b  = (const float*)d_in[6];
  const float* f_W  = (const float*)d_in[7];
  const float* f_b  = (const float*)d_in[8];
  const float* c1_W = (const float*)d_in[9];
  const float* c1_b = (const float*)d_in[10];
  const float* c2_W = (const float*)d_in[11];
  const float* c2_b = (const float*)d_in[12];
  const float* n1_g = (const float*)d_in[13];
  const float* n1_b = (const float*)d_in[14];
  const float* n2_g = (const float*)d_in[15];
  const float* n2_b = (const float*)d_in[16];
  const float* e_W  = (const float*)d_in[17];
  const float* e_b  = (const float*)d_in[18];
  const float* r_W  = (const float*)d_in[19];
  const float* r_b  = (const float*)d_in[20];

  int n_u = in_sizes[0] / 64;
  int n_f = in_sizes[1] / HID;
  int n   = n_u + n_f;
  int E   = in_sizes[2] / 2;
  int Ep  = in_sizes[3];

  const int* src = ei;
  const int* dst = ei + E;

  float*  x      = (float*)d_ws;                   // n*HID f32
  float*  xw     = x + (size_t)n * HID;            // n*HID f32
  float*  dinv   = xw + (size_t)n * HID;           // n f32
  float*  colw   = dinv + n;                       // E f32
  int*    cnt    = (int*)(colw + E);               // n int
  int*    rowptr = cnt + n;                        // n+1 int
  int*    cursor = rowptr + n + 1;                 // n int
  int*    colsrc = cursor + n;                     // E int
  float4* table  = (float4*)(colsrc + E);          // n float4

  // ---- build CSR by dst + dinv ----
  zero_int_kernel<<<(n + 255) / 256, 256, 0, stream>>>(cnt, n);
  hist_kernel<<<(E + 255) / 256, 256, 0, stream>>>(dst, cnt, E);
  scan_kernel<<<1, SCAN_T, 0, stream>>>(cnt, rowptr, dinv, n);
  zero_int_kernel<<<(n + 255) / 256, 256, 0, stream>>>(cursor, n);
  fill_csr_kernel<<<(E + 255) / 256, 256, 0, stream>>>(src, dst, rowptr, cursor, dinv,
                                                       colsrc, colw, E);

  // ---- input embeddings ----
  dense_kernel<64><<<n_u, HID, 0, stream>>>(u_feat, u_W, u_b, x, n_u);
  dense_kernel<HID><<<n_f, HID, 0, stream>>>(f_feat, f_W, f_b, x + (size_t)n_u * HID, n_f);

  // ---- 2 GCN layers ----
  for (int layer = 0; layer < 2; ++layer) {
    const float* cW = layer ? c2_W : c1_W;
    const float* cb = layer ? c2_b : c1_b;
    const float* g  = layer ? n2_g : n1_g;
    const float* bb = layer ? n2_b : n1_b;
    dense_kernel<HID><<<n, HID, 0, stream>>>(x, cW, nullptr, xw, n);
    gather_norm_kernel<<<(n + 3) / 4, 256, 0, stream>>>(rowptr, colsrc, colw, xw, dinv,
                                                        cb, g, bb, x, n);
  }

  // ---- prediction heads: per-node projections, then per-pair combine ----
  node_proj_kernel<<<(n + 3) / 4, 256, 0, stream>>>(x, e_W, r_W, table, n);
  float* out_exist  = (float*)d_out;
  float* out_rating = out_exist + Ep;
  pair_kernel<<<(Ep + 255) / 256, 256, 0, stream>>>(eu, ef, table, e_b, r_b,
                                                    out_exist, out_rating, Ep);
}

// Round 4
// 986.823 us; speedup vs baseline: 4.2603x; 1.0864x over previous
//
#include <hip/hip_runtime.h>
#include <hip/hip_bf16.h>
#include <math.h>

#define HID 128
#define SLOPE 0.01f
#define LN_EPS 1e-5f
#define SCAN_T 1024

__device__ __forceinline__ float bf16lo(unsigned int v) {
  unsigned int b = v << 16;
  return __builtin_bit_cast(float, b);
}
__device__ __forceinline__ float bf16hi(unsigned int v) {
  unsigned int b = v & 0xFFFF0000u;
  return __builtin_bit_cast(float, b);
}

__global__ void zero_int_kernel(int* __restrict__ p, int n) {
  int i = blockIdx.x * blockDim.x + threadIdx.x;
  if (i < n) p[i] = 0;
}

__global__ void hist_kernel(const int* __restrict__ dst, int* __restrict__ cnt, int E) {
  int i = blockIdx.x * blockDim.x + threadIdx.x;
  if (i < E) atomicAdd(&cnt[dst[i]], 1);
}

// single-block scan: cnt[0..n) -> rowptr (exclusive), dinv = rsqrt(cnt+1)
__global__ void scan_kernel(const int* __restrict__ cnt, int* __restrict__ rowptr,
                            float* __restrict__ dinv, int n) {
  __shared__ int ssum[SCAN_T];
  int t = threadIdx.x;
  int chunk = (n + SCAN_T - 1) / SCAN_T;
  int beg = t * chunk, end = min(beg + chunk, n);
  int s = 0;
  for (int i = beg; i < end; ++i) s += cnt[i];
  ssum[t] = s;
  __syncthreads();
  for (int off = 1; off < SCAN_T; off <<= 1) {
    int v = (t >= off) ? ssum[t - off] : 0;
    __syncthreads();
    ssum[t] += v;
    __syncthreads();
  }
  int pre = (t == 0) ? 0 : ssum[t - 1];
  for (int i = beg; i < end; ++i) {
    rowptr[i] = pre;
    int c = cnt[i];
    dinv[i] = rsqrtf((float)(c + 1));
    pre += c;
  }
  if (t == SCAN_T - 1) rowptr[n] = pre;
}

// countdown-fill: one random 4B store per edge; consumes cnt
__global__ void fill_csr_kernel(const int* __restrict__ src, const int* __restrict__ dst,
                                const int* __restrict__ rowptr, int* __restrict__ cnt,
                                int* __restrict__ colsrc, int E) {
  int e = blockIdx.x * blockDim.x + threadIdx.x;
  if (e >= E) return;
  int s = src[e], d = dst[e];
  int old = atomicSub(&cnt[d], 1);
  colsrc[rowptr[d] + old - 1] = s;
}

// out[n][j] = bias[j] + sum_k feat[n][k] * W[k][j]   (block = 1 row, 128 threads, f32 out)
template<int DIM>
__global__ void dense_kernel(const float* __restrict__ feat,
                             const float* __restrict__ W,
                             const float* __restrict__ bias,
                             float* __restrict__ out, int nrows) {
  __shared__ float sf[DIM];
  int n = blockIdx.x;
  int j = threadIdx.x;
  if (j < DIM) sf[j] = feat[(size_t)n * DIM + j];
  __syncthreads();
  float acc = bias ? bias[j] : 0.0f;
#pragma unroll
  for (int k = 0; k < DIM; ++k) acc = fmaf(sf[k], W[k * HID + j], acc);
  out[(size_t)n * HID + j] = acc;
}

// layer dense: x(f32) @ W -> xw packed bf16 (no bias; conv bias folded into gather)
__global__ void dense_bf16_kernel(const float* __restrict__ feat,
                                  const float* __restrict__ W,
                                  unsigned int* __restrict__ out, int nrows) {
  __shared__ float sf[HID];
  int n = blockIdx.x;
  int j = threadIdx.x;
  sf[j] = feat[(size_t)n * HID + j];
  __syncthreads();
  float acc = 0.0f;
#pragma unroll
  for (int k = 0; k < HID; ++k) acc = fmaf(sf[k], W[k * HID + j], acc);
  float other = __shfl_xor(acc, 1);
  if ((j & 1) == 0) {
    __hip_bfloat16 b0 = __float2bfloat16(acc);
    __hip_bfloat16 b1 = __float2bfloat16(other);
    unsigned int p = (unsigned int)__builtin_bit_cast(unsigned short, b0) |
                     ((unsigned int)__builtin_bit_cast(unsigned short, b1) << 16);
    out[((size_t)n * HID + j) >> 1] = p;
  }
}

// One wave per dst node: acc = xw[d]*dinv[d]^2 + sum_edges xw[s]*dinv[s]*dinv[d];
// + conv bias, LayerNorm * g + b, LeakyReLU.
// PROJ=false: write f32 x row.  PROJ=true: write only 4 head-dots to table.
template<bool PROJ>
__global__ void gather_norm_kernel(const int* __restrict__ rowptr,
                                   const int* __restrict__ colsrc,
                                   const unsigned int* __restrict__ xwb,  // packed bf16
                                   const float* __restrict__ dinv,
                                   const float* __restrict__ cb,
                                   const float* __restrict__ g,
                                   const float* __restrict__ b,
                                   const float* __restrict__ eW,
                                   const float* __restrict__ rW,
                                   float* __restrict__ outx,
                                   float4* __restrict__ table, int n_nodes) {
  int d = blockIdx.x * 4 + (threadIdx.x >> 6);
  if (d >= n_nodes) return;
  int lane = threadIdx.x & 63;
  float wd = dinv[d];
  float wself = wd * wd;
  unsigned int v = xwb[(size_t)d * (HID / 2) + lane];
  float ax = bf16lo(v) * wself, ay = bf16hi(v) * wself;
  int beg = rowptr[d], end = rowptr[d + 1];
  int j = beg;
  for (; j + 1 < end; j += 2) {
    int s0 = colsrc[j], s1 = colsrc[j + 1];
    float w0 = dinv[s0] * wd, w1 = dinv[s1] * wd;
    unsigned int a0 = xwb[(size_t)s0 * (HID / 2) + lane];
    unsigned int a1 = xwb[(size_t)s1 * (HID / 2) + lane];
    ax = fmaf(bf16lo(a0), w0, ax);
    ay = fmaf(bf16hi(a0), w0, ay);
    ax = fmaf(bf16lo(a1), w1, ax);
    ay = fmaf(bf16hi(a1), w1, ay);
  }
  if (j < end) {
    int s0 = colsrc[j];
    float w0 = dinv[s0] * wd;
    unsigned int a0 = xwb[(size_t)s0 * (HID / 2) + lane];
    ax = fmaf(bf16lo(a0), w0, ax);
    ay = fmaf(bf16hi(a0), w0, ay);
  }
  float2 cb2 = reinterpret_cast<const float2*>(cb)[lane];
  ax += cb2.x; ay += cb2.y;
  float s = ax + ay;
#pragma unroll
  for (int m = 1; m < 64; m <<= 1) s += __shfl_xor(s, m);
  float mu = s * (1.0f / HID);
  float dx = ax - mu, dy = ay - mu;
  float sq = dx * dx + dy * dy;
#pragma unroll
  for (int m = 1; m < 64; m <<= 1) sq += __shfl_xor(sq, m);
  float rs = rsqrtf(sq * (1.0f / HID) + LN_EPS);
  float2 g2 = reinterpret_cast<const float2*>(g)[lane];
  float2 b2 = reinterpret_cast<const float2*>(b)[lane];
  float o0 = dx * rs * g2.x + b2.x;
  float o1 = dy * rs * g2.y + b2.y;
  o0 = o0 >= 0.0f ? o0 : SLOPE * o0;
  o1 = o1 >= 0.0f ? o1 : SLOPE * o1;
  if (!PROJ) {
    reinterpret_cast<float2*>(outx + (size_t)d * HID)[lane] = make_float2(o0, o1);
  } else {
    float2 eWu = reinterpret_cast<const float2*>(eW)[lane];
    float2 eWf = reinterpret_cast<const float2*>(eW + HID)[lane];
    float2 rWu = reinterpret_cast<const float2*>(rW)[lane];
    float2 rWf = reinterpret_cast<const float2*>(rW + HID)[lane];
    float pa = o0 * eWu.x + o1 * eWu.y;
    float pb = o0 * eWf.x + o1 * eWf.y;
    float pc = o0 * rWu.x + o1 * rWu.y;
    float pd = o0 * rWf.x + o1 * rWf.y;
#pragma unroll
    for (int m = 1; m < 64; m <<= 1) {
      pa += __shfl_xor(pa, m);
      pb += __shfl_xor(pb, m);
      pc += __shfl_xor(pc, m);
      pd += __shfl_xor(pd, m);
    }
    if (lane == 0) table[d] = make_float4(pa, pb, pc, pd);
  }
}

// one thread per prediction pair
__global__ void pair_kernel(const int* __restrict__ eu, const int* __restrict__ ef,
                            const float4* __restrict__ table,
                            const float* __restrict__ eb, const float* __restrict__ rb,
                            float* __restrict__ out_exist, float* __restrict__ out_rating,
                            int Ep) {
  int i = blockIdx.x * blockDim.x + threadIdx.x;
  if (i >= Ep) return;
  float4 tu = table[eu[i]];
  float4 tf = table[ef[i]];
  float pe = tu.x + tf.y + eb[0];
  float pr = tu.z + tf.w + rb[0];
  out_exist[i]  = 1.0f / (1.0f + expf(-pe));
  out_rating[i] = 1.0f + 4.0f / (1.0f + expf(-pr));
}

extern "C" void kernel_launch(void* const* d_in, const int* in_sizes, int n_in,
                              void* d_out, int out_size, void* d_ws, size_t ws_size,
                              hipStream_t stream) {
  const float* u_feat = (const float*)d_in[0];
  const float* f_feat = (const float*)d_in[1];
  const int*   ei     = (const int*)d_in[2];
  const int*   eu     = (const int*)d_in[3];
  const int*   ef     = (const int*)d_in[4];
  const float* u_W  = (const float*)d_in[5];
  const float* u_b  = (const float*)d_in[6];
  const float* f_W  = (const float*)d_in[7];
  const float* f_b  = (const float*)d_in[8];
  const float* c1_W = (const float*)d_in[9];
  const float* c1_b = (const float*)d_in[10];
  const float* c2_W = (const float*)d_in[11];
  const float* c2_b = (const float*)d_in[12];
  const float* n1_g = (const float*)d_in[13];
  const float* n1_b = (const float*)d_in[14];
  const float* n2_g = (const float*)d_in[15];
  const float* n2_b = (const float*)d_in[16];
  const float* e_W  = (const float*)d_in[17];
  const float* e_b  = (const float*)d_in[18];
  const float* r_W  = (const float*)d_in[19];
  const float* r_b  = (const float*)d_in[20];

  int n_u = in_sizes[0] / 64;
  int n_f = in_sizes[1] / HID;
  int n   = n_u + n_f;
  int E   = in_sizes[2] / 2;
  int Ep  = in_sizes[3];

  const int* src = ei;
  const int* dst = ei + E;

  float*        x      = (float*)d_ws;                        // n*HID f32
  unsigned int* xwb    = (unsigned int*)(x + (size_t)n * HID); // n*HID/2 uint (bf16x2)
  float4*       table  = (float4*)(xwb + (size_t)n * (HID / 2)); // n float4
  float*        dinv   = (float*)(table + n);                 // n f32
  int*          cnt    = (int*)(dinv + n);                    // n int
  int*          rowptr = cnt + n;                             // n+1 int
  int*          colsrc = rowptr + n + 1;                      // E int

  // ---- build CSR by dst + dinv ----
  zero_int_kernel<<<(n + 255) / 256, 256, 0, stream>>>(cnt, n);
  hist_kernel<<<(E + 255) / 256, 256, 0, stream>>>(dst, cnt, E);
  scan_kernel<<<1, SCAN_T, 0, stream>>>(cnt, rowptr, dinv, n);
  fill_csr_kernel<<<(E + 255) / 256, 256, 0, stream>>>(src, dst, rowptr, cnt, colsrc, E);

  // ---- input embeddings (f32 x) ----
  dense_kernel<64><<<n_u, HID, 0, stream>>>(u_feat, u_W, u_b, x, n_u);
  dense_kernel<HID><<<n_f, HID, 0, stream>>>(f_feat, f_W, f_b, x + (size_t)n_u * HID, n_f);

  // ---- layer 1 ----
  dense_bf16_kernel<<<n, HID, 0, stream>>>(x, c1_W, xwb, n);
  gather_norm_kernel<false><<<(n + 3) / 4, 256, 0, stream>>>(
      rowptr, colsrc, xwb, dinv, c1_b, n1_g, n1_b, nullptr, nullptr, x, nullptr, n);

  // ---- layer 2 (fused prediction-head projection) ----
  dense_bf16_kernel<<<n, HID, 0, stream>>>(x, c2_W, xwb, n);
  gather_norm_kernel<true><<<(n + 3) / 4, 256, 0, stream>>>(
      rowptr, colsrc, xwb, dinv, c2_b, n2_g, n2_b, e_W, r_W, nullptr, table, n);

  // ---- per-pair combine ----
  float* out_exist  = (float*)d_out;
  float* out_rating = out_exist + Ep;
  pair_kernel<<<(Ep + 255) / 256, 256, 0, stream>>>(eu, ef, table, e_b, r_b,
                                                    out_exist, out_rating, Ep);
}

// Round 5
// 637.040 us; speedup vs baseline: 6.5995x; 1.5491x over previous
//
#include <hip/hip_runtime.h>
#include <hip/hip_bf16.h>
#include <math.h>

#define HID 128
#define SLOPE 0.01f
#define LN_EPS 1e-5f
#define NB_SCAN 256
#define NT_SCAN 256

__device__ __forceinline__ float bf16lo(unsigned int v) {
  unsigned int b = v << 16;
  return __builtin_bit_cast(float, b);
}
__device__ __forceinline__ float bf16hi(unsigned int v) {
  unsigned int b = v & 0xFFFF0000u;
  return __builtin_bit_cast(float, b);
}
__device__ __forceinline__ unsigned int pack_bf16(float lo, float hi) {
  __hip_bfloat16 a = __float2bfloat16(lo);
  __hip_bfloat16 b = __float2bfloat16(hi);
  return (unsigned int)__builtin_bit_cast(unsigned short, a) |
         ((unsigned int)__builtin_bit_cast(unsigned short, b) << 16);
}

__global__ void zero_int_kernel(int* __restrict__ p, int n) {
  int i = blockIdx.x * blockDim.x + threadIdx.x;
  if (i < n) p[i] = 0;
}

__global__ void hist_kernel(const int* __restrict__ dst, int* __restrict__ cnt, int E) {
  int i = blockIdx.x * blockDim.x + threadIdx.x;
  if (i < E) atomicAdd(&cnt[dst[i]], 1);
}

// pass1: per-block sums of cnt chunks
__global__ void scan_pass1(const int* __restrict__ cnt, int* __restrict__ blocksum, int n) {
  __shared__ int ss[NT_SCAN];
  int K = (n + NB_SCAN * NT_SCAN - 1) / (NB_SCAN * NT_SCAN);
  int t = threadIdx.x, b = blockIdx.x;
  int beg = (b * NT_SCAN + t) * K;
  int end = min(beg + K, n);
  int s = 0;
  for (int i = beg; i < end; ++i) s += cnt[i];
  ss[t] = s;
  __syncthreads();
  for (int off = NT_SCAN / 2; off > 0; off >>= 1) {
    if (t < off) ss[t] += ss[t + off];
    __syncthreads();
  }
  if (t == 0) blocksum[b] = ss[0];
}

// pass2: exclusive scan of NB_SCAN block sums (single block)
__global__ void scan_pass2(int* __restrict__ blocksum) {
  __shared__ int ss[NB_SCAN];
  int t = threadIdx.x;
  ss[t] = blocksum[t];
  __syncthreads();
  for (int off = 1; off < NB_SCAN; off <<= 1) {
    int v = (t >= off) ? ss[t - off] : 0;
    __syncthreads();
    ss[t] += v;
    __syncthreads();
  }
  blocksum[t] = (t == 0) ? 0 : ss[t - 1];
}

// pass3: write rowptr (exclusive) + dinv
__global__ void scan_pass3(const int* __restrict__ cnt, const int* __restrict__ blockoff,
                           int* __restrict__ rowptr, float* __restrict__ dinv, int n) {
  __shared__ int ss[NT_SCAN];
  int K = (n + NB_SCAN * NT_SCAN - 1) / (NB_SCAN * NT_SCAN);
  int t = threadIdx.x, b = blockIdx.x;
  int beg = (b * NT_SCAN + t) * K;
  int end = min(beg + K, n);
  int s = 0;
  for (int i = beg; i < end; ++i) s += cnt[i];
  ss[t] = s;
  __syncthreads();
  for (int off = 1; off < NT_SCAN; off <<= 1) {
    int v = (t >= off) ? ss[t - off] : 0;
    __syncthreads();
    ss[t] += v;
    __syncthreads();
  }
  int pre = blockoff[b] + ((t == 0) ? 0 : ss[t - 1]);
  for (int i = beg; i < end; ++i) {
    rowptr[i] = pre;
    int c = cnt[i];
    dinv[i] = rsqrtf((float)(c + 1));
    pre += c;
    if (i == n - 1) rowptr[n] = pre;
  }
}

// countdown-fill: one random 4B store per edge; consumes cnt
__global__ void fill_csr_kernel(const int* __restrict__ src, const int* __restrict__ dst,
                                const int* __restrict__ rowptr, int* __restrict__ cnt,
                                int* __restrict__ colsrc, int E) {
  int e = blockIdx.x * blockDim.x + threadIdx.x;
  if (e >= E) return;
  int s = src[e], d = dst[e];
  int old = atomicSub(&cnt[d], 1);
  colsrc[rowptr[d] + old - 1] = s;
}

// Multi-row dense: out[r][j] = bias[j] + sum_k feat[r][k]*W[k][j].
// W staged in LDS as packed bf16 pairs over k; 16 rows per block.
template<int DIM, int ROWS, bool BF16OUT>
__global__ __launch_bounds__(256) void dense_mr_kernel(
    const float* __restrict__ feat, const float* __restrict__ W,
    const float* __restrict__ bias,
    float* __restrict__ outf, unsigned int* __restrict__ outb, int nrows) {
  __shared__ unsigned int sWp[(DIM / 2) * HID];  // bf16x2 packed over k-pairs
  __shared__ float sf[ROWS * DIM];
  int tid = threadIdx.x;
  int base = blockIdx.x * ROWS;

  // stage W -> packed bf16
  const int UNITS = (DIM / 2) * (HID / 4);
  for (int u = tid; u < UNITS; u += 256) {
    int k2 = u >> 5;
    int j4 = (u & 31) << 2;
    float4 a = *reinterpret_cast<const float4*>(&W[(size_t)(2 * k2) * HID + j4]);
    float4 b = *reinterpret_cast<const float4*>(&W[(size_t)(2 * k2 + 1) * HID + j4]);
    sWp[k2 * HID + j4 + 0] = pack_bf16(a.x, b.x);
    sWp[k2 * HID + j4 + 1] = pack_bf16(a.y, b.y);
    sWp[k2 * HID + j4 + 2] = pack_bf16(a.z, b.z);
    sWp[k2 * HID + j4 + 3] = pack_bf16(a.w, b.w);
  }
  // stage rows (contiguous)
  int nr = min(ROWS, nrows - base);
  int tot = nr * DIM;
  const float* fp = feat + (size_t)base * DIM;
  for (int i = tid * 4; i < tot; i += 1024) {
    *reinterpret_cast<float4*>(&sf[i]) = *reinterpret_cast<const float4*>(&fp[i]);
  }
  __syncthreads();

  int j = tid & 127;
  int rr = tid >> 7;  // 0/1
  float bj = bias ? bias[j] : 0.0f;
  for (int r = rr; r < nr; r += 2) {
    float acc = bj;
#pragma unroll
    for (int k2 = 0; k2 < DIM / 2; ++k2) {
      unsigned int w2 = sWp[k2 * HID + j];
      acc = fmaf(sf[r * DIM + 2 * k2], bf16lo(w2), acc);
      acc = fmaf(sf[r * DIM + 2 * k2 + 1], bf16hi(w2), acc);
    }
    if (BF16OUT) {
      float other = __shfl_xor(acc, 1);
      if ((j & 1) == 0) {
        outb[((size_t)(base + r) * HID + j) >> 1] = pack_bf16(acc, other);
      }
    } else {
      outf[(size_t)(base + r) * HID + j] = acc;
    }
  }
}

// One wave per dst node: acc = xw[d]*dinv[d]^2 + sum_edges xw[s]*dinv[s]*dinv[d];
// + conv bias, LayerNorm * g + b, LeakyReLU.
// PROJ=false: write f32 x row.  PROJ=true: write only 4 head-dots to table.
template<bool PROJ>
__global__ void gather_norm_kernel(const int* __restrict__ rowptr,
                                   const int* __restrict__ colsrc,
                                   const unsigned int* __restrict__ xwb,  // packed bf16
                                   const float* __restrict__ dinv,
                                   const float* __restrict__ cb,
                                   const float* __restrict__ g,
                                   const float* __restrict__ b,
                                   const float* __restrict__ eW,
                                   const float* __restrict__ rW,
                                   float* __restrict__ outx,
                                   float4* __restrict__ table, int n_nodes) {
  int d = blockIdx.x * 4 + (threadIdx.x >> 6);
  if (d >= n_nodes) return;
  int lane = threadIdx.x & 63;
  float wd = dinv[d];
  float wself = wd * wd;
  unsigned int v = xwb[(size_t)d * (HID / 2) + lane];
  float ax = bf16lo(v) * wself, ay = bf16hi(v) * wself;
  int beg = rowptr[d], end = rowptr[d + 1];
  int j = beg;
  for (; j + 1 < end; j += 2) {
    int s0 = colsrc[j], s1 = colsrc[j + 1];
    float w0 = dinv[s0] * wd, w1 = dinv[s1] * wd;
    unsigned int a0 = xwb[(size_t)s0 * (HID / 2) + lane];
    unsigned int a1 = xwb[(size_t)s1 * (HID / 2) + lane];
    ax = fmaf(bf16lo(a0), w0, ax);
    ay = fmaf(bf16hi(a0), w0, ay);
    ax = fmaf(bf16lo(a1), w1, ax);
    ay = fmaf(bf16hi(a1), w1, ay);
  }
  if (j < end) {
    int s0 = colsrc[j];
    float w0 = dinv[s0] * wd;
    unsigned int a0 = xwb[(size_t)s0 * (HID / 2) + lane];
    ax = fmaf(bf16lo(a0), w0, ax);
    ay = fmaf(bf16hi(a0), w0, ay);
  }
  float2 cb2 = reinterpret_cast<const float2*>(cb)[lane];
  ax += cb2.x; ay += cb2.y;
  float s = ax + ay;
#pragma unroll
  for (int m = 1; m < 64; m <<= 1) s += __shfl_xor(s, m);
  float mu = s * (1.0f / HID);
  float dx = ax - mu, dy = ay - mu;
  float sq = dx * dx + dy * dy;
#pragma unroll
  for (int m = 1; m < 64; m <<= 1) sq += __shfl_xor(sq, m);
  float rs = rsqrtf(sq * (1.0f / HID) + LN_EPS);
  float2 g2 = reinterpret_cast<const float2*>(g)[lane];
  float2 b2 = reinterpret_cast<const float2*>(b)[lane];
  float o0 = dx * rs * g2.x + b2.x;
  float o1 = dy * rs * g2.y + b2.y;
  o0 = o0 >= 0.0f ? o0 : SLOPE * o0;
  o1 = o1 >= 0.0f ? o1 : SLOPE * o1;
  if (!PROJ) {
    reinterpret_cast<float2*>(outx + (size_t)d * HID)[lane] = make_float2(o0, o1);
  } else {
    float2 eWu = reinterpret_cast<const float2*>(eW)[lane];
    float2 eWf = reinterpret_cast<const float2*>(eW + HID)[lane];
    float2 rWu = reinterpret_cast<const float2*>(rW)[lane];
    float2 rWf = reinterpret_cast<const float2*>(rW + HID)[lane];
    float pa = o0 * eWu.x + o1 * eWu.y;
    float pb = o0 * eWf.x + o1 * eWf.y;
    float pc = o0 * rWu.x + o1 * rWu.y;
    float pd = o0 * rWf.x + o1 * rWf.y;
#pragma unroll
    for (int m = 1; m < 64; m <<= 1) {
      pa += __shfl_xor(pa, m);
      pb += __shfl_xor(pb, m);
      pc += __shfl_xor(pc, m);
      pd += __shfl_xor(pd, m);
    }
    if (lane == 0) table[d] = make_float4(pa, pb, pc, pd);
  }
}

// one thread per prediction pair
__global__ void pair_kernel(const int* __restrict__ eu, const int* __restrict__ ef,
                            const float4* __restrict__ table,
                            const float* __restrict__ eb, const float* __restrict__ rb,
                            float* __restrict__ out_exist, float* __restrict__ out_rating,
                            int Ep) {
  int i = blockIdx.x * blockDim.x + threadIdx.x;
  if (i >= Ep) return;
  float4 tu = table[eu[i]];
  float4 tf = table[ef[i]];
  float pe = tu.x + tf.y + eb[0];
  float pr = tu.z + tf.w + rb[0];
  out_exist[i]  = 1.0f / (1.0f + expf(-pe));
  out_rating[i] = 1.0f + 4.0f / (1.0f + expf(-pr));
}

extern "C" void kernel_launch(void* const* d_in, const int* in_sizes, int n_in,
                              void* d_out, int out_size, void* d_ws, size_t ws_size,
                              hipStream_t stream) {
  const float* u_feat = (const float*)d_in[0];
  const float* f_feat = (const float*)d_in[1];
  const int*   ei     = (const int*)d_in[2];
  const int*   eu     = (const int*)d_in[3];
  const int*   ef     = (const int*)d_in[4];
  const float* u_W  = (const float*)d_in[5];
  const float* u_b  = (const float*)d_in[6];
  const float* f_W  = (const float*)d_in[7];
  const float* f_b  = (const float*)d_in[8];
  const float* c1_W = (const float*)d_in[9];
  const float* c1_b = (const float*)d_in[10];
  const float* c2_W = (const float*)d_in[11];
  const float* c2_b = (const float*)d_in[12];
  const float* n1_g = (const float*)d_in[13];
  const float* n1_b = (const float*)d_in[14];
  const float* n2_g = (const float*)d_in[15];
  const float* n2_b = (const float*)d_in[16];
  const float* e_W  = (const float*)d_in[17];
  const float* e_b  = (const float*)d_in[18];
  const float* r_W  = (const float*)d_in[19];
  const float* r_b  = (const float*)d_in[20];

  int n_u = in_sizes[0] / 64;
  int n_f = in_sizes[1] / HID;
  int n   = n_u + n_f;
  int E   = in_sizes[2] / 2;
  int Ep  = in_sizes[3];

  const int* src = ei;
  const int* dst = ei + E;

  float*        x      = (float*)d_ws;                           // n*HID f32
  unsigned int* xwb    = (unsigned int*)(x + (size_t)n * HID);   // n*HID/2 uint (bf16x2)
  float4*       table  = (float4*)(xwb + (size_t)n * (HID / 2)); // n float4
  float*        dinv   = (float*)(table + n);                    // n f32
  int*          cnt    = (int*)(dinv + n);                       // n int
  int*          rowptr = cnt + n;                                // n+1 int
  int*          blocksum = rowptr + n + 1;                       // NB_SCAN int
  int*          colsrc = blocksum + NB_SCAN;                     // E int

  // ---- build CSR by dst + dinv ----
  zero_int_kernel<<<(n + 255) / 256, 256, 0, stream>>>(cnt, n);
  hist_kernel<<<(E + 255) / 256, 256, 0, stream>>>(dst, cnt, E);
  scan_pass1<<<NB_SCAN, NT_SCAN, 0, stream>>>(cnt, blocksum, n);
  scan_pass2<<<1, NB_SCAN, 0, stream>>>(blocksum);
  scan_pass3<<<NB_SCAN, NT_SCAN, 0, stream>>>(cnt, blocksum, rowptr, dinv, n);
  fill_csr_kernel<<<(E + 255) / 256, 256, 0, stream>>>(src, dst, rowptr, cnt, colsrc, E);

  // ---- input embeddings (f32 x) ----
  dense_mr_kernel<64, 16, false><<<(n_u + 15) / 16, 256, 0, stream>>>(
      u_feat, u_W, u_b, x, nullptr, n_u);
  dense_mr_kernel<128, 16, false><<<(n_f + 15) / 16, 256, 0, stream>>>(
      f_feat, f_W, f_b, x + (size_t)n_u * HID, nullptr, n_f);

  // ---- layer 1 ----
  dense_mr_kernel<128, 16, true><<<(n + 15) / 16, 256, 0, stream>>>(
      x, c1_W, nullptr, nullptr, xwb, n);
  gather_norm_kernel<false><<<(n + 3) / 4, 256, 0, stream>>>(
      rowptr, colsrc, xwb, dinv, c1_b, n1_g, n1_b, nullptr, nullptr, x, nullptr, n);

  // ---- layer 2 (fused prediction-head projection) ----
  dense_mr_kernel<128, 16, true><<<(n + 15) / 16, 256, 0, stream>>>(
      x, c2_W, nullptr, nullptr, xwb, n);
  gather_norm_kernel<true><<<(n + 3) / 4, 256, 0, stream>>>(
      rowptr, colsrc, xwb, dinv, c2_b, n2_g, n2_b, e_W, r_W, nullptr, table, n);

  // ---- per-pair combine ----
  float* out_exist  = (float*)d_out;
  float* out_rating = out_exist + Ep;
  pair_kernel<<<(Ep + 255) / 256, 256, 0, stream>>>(eu, ef, table, e_b, r_b,
                                                    out_exist, out_rating, Ep);
}